// Round 2
// baseline (339.064 us; speedup 1.0000x reference)
//
#include <hip/hip_runtime.h>

// Tensor-train forward, B=4096 N=8 F=64 D=64 C=10.
// R3: R2 p-split fix. Grid 256 = 64 sample-groups (64 samples) x 4
// p-quarters; each block reads only 1/4 of each core per step (128 KB vs
// 512 KB), cutting the per-CU L2 A-stream ~4x and activating all 256 CUs
// (was 128). Partial v exchanged via ws with agent-scope atomics + flag
// polling; bounded poll with compute-it-yourself fallback => deadlock-free
// without cooperative launch. Final (core_first) step p-split with
// atomicAdd into zeroed out.
// Fix vs R2: final out stage was `if (tid < 640)` with only 512 threads ->
// classes 8,9 never written (absmax 0.73). Now grid-strided. Flag protocol
// upgraded to release/acquire.

typedef _Float16 half8 __attribute__((ext_vector_type(8)));
typedef _Float16 half4 __attribute__((ext_vector_type(4)));
typedef float f32x4 __attribute__((ext_vector_type(4)));
typedef unsigned long long u64;

#define LAST_OFF   0
#define MID_OFF    4096
#define MID_SZ     262144
#define FIRST_OFF  1576960
#define N_FRAGS    3208
#define PART_BYTE_OFF (16u << 20)   // partial-v regions: [step<6][g<64][q<4] * 8192 B
#define FLAG_BYTE_OFF (48u << 20)   // flags: u32 [step<6][g<64][q<4]
#define POLL_MAX   20000
#define SWZ_TOTAL  (N_FRAGS * 64 + 40960 + 1536)

// ---------- prologue: fp32 cores -> f16 MFMA-A frags; zero out + flags ----------
__global__ __launch_bounds__(256) void tt_swz(
    const float* __restrict__ cf,   // core_first (10,64,64)  [c][p][r]
    const float* __restrict__ cm,   // cores_mid  (6,64,64,64)[ci][l][p][r]
    const float* __restrict__ cl,   // core_last  (64,64)     [l][p]
    _Float16* __restrict__ ws,
    float* __restrict__ out)
{
  int gid = blockIdx.x * 256 + threadIdx.x;
  if (gid < N_FRAGS * 64) {
    int lane = gid & 63, frag = gid >> 6;
    int quad = lane >> 4, m16 = lane & 15;
    half8 hv;
    _Float16* dst;
    if (frag < 8) {                       // core_last: rows l (4 tiles), k = p
      int t = frag >> 1, kt = frag & 1;
      int l = t * 16 + m16;
      const float* s = cl + l * 64 + kt * 32 + quad * 8;
#pragma unroll
      for (int j = 0; j < 8; ++j) hv[j] = (_Float16)s[j];
      dst = ws + LAST_OFF + (size_t)((t * 2 + kt) * 64 + lane) * 8;
    } else if (frag < 8 + 3072) {         // mid cores: rows (p,l), k = r
      int f2 = frag - 8;
      int ci = f2 >> 9, rem = f2 & 511;
      int t = rem >> 1, kt = rem & 1;
      int l = (t & 3) * 16 + m16, p = t >> 2;
      const float* s = cm + (((size_t)ci * 64 + l) * 64 + p) * 64 + kt * 32 + quad * 8;
#pragma unroll
      for (int j = 0; j < 8; ++j) hv[j] = (_Float16)s[j];
      dst = ws + MID_OFF + (size_t)ci * MID_SZ + (size_t)(rem * 64 + lane) * 8;
    } else {                              // core_first: rows c (pad 16), k = r
      int f2 = frag - 3080;
      int t = f2 >> 1, kt = f2 & 1;
      int c = m16, p = t;
      if (c < 10) {
        const float* s = cf + ((size_t)(c * 64 + p)) * 64 + kt * 32 + quad * 8;
#pragma unroll
        for (int j = 0; j < 8; ++j) hv[j] = (_Float16)s[j];
      } else {
#pragma unroll
        for (int j = 0; j < 8; ++j) hv[j] = (_Float16)0.f;
      }
      dst = ws + FIRST_OFF + (size_t)((t * 2 + kt) * 64 + lane) * 8;
    }
    *(half8*)dst = hv;
    return;
  }
  int e = gid - N_FRAGS * 64;
  if (e < 40960) { out[e] = 0.f; return; }     // zero out for atomicAdd epilogue
  e -= 40960;
  if (e < 1536) {                              // zero exchange flags
    unsigned* flags = (unsigned*)((char*)ws + FLAG_BYTE_OFF);
    __hip_atomic_store(&flags[e], 0u, __ATOMIC_RELAXED, __HIP_MEMORY_SCOPE_AGENT);
  }
}

// ------------------- main chain: 256 blocks x 512 threads -----------------
__global__ __launch_bounds__(512) void tt_main(
    const float* __restrict__ x,        // (4096, 8, 64)
    _Float16* __restrict__ ws,
    float* __restrict__ out)            // (4096, 10)
{
  __shared__ __align__(16) _Float16 Xs[64][72];     // [s][p] current carriage
  __shared__ __align__(16) _Float16 Vc[64][72];     // v state [s][r]
  __shared__ __align__(16) _Float16 Vt[2][64][72];  // per-pg partials
  __shared__ float RedL[10][68];                    // final c-output reduce
  __shared__ int status[4];

  const int tid = threadIdx.x;
  const int w = tid >> 6, lane = tid & 63;
  const int quad = lane >> 4, sl = lane & 15;
  const int b = blockIdx.x;
  // group-of-4 on one XCD (assumes round-robin XCD = b&7; perf-only assumption)
  const int q = (b >> 3) & 3;                    // p-quarter
  const int g = (b & 7) | ((b >> 5) << 3);       // sample group [0,64)
  const int s0 = g * 64;
  const int pg = w >> 2, lt = w & 3;
  const int cs = tid >> 3, l8 = (tid & 7) * 8;   // combine-stage mapping

  unsigned* flags = (unsigned*)((char*)ws + FLAG_BYTE_OFF);

  auto stageX = [&](int n) {
    int s = tid >> 3, p8 = (tid & 7) * 8;
    const float* src = x + ((size_t)(s0 + s) * 8 + n) * 64 + p8;
    float4 a = *(const float4*)src;
    float4 b4 = *(const float4*)(src + 4);
    half8 h;
    h[0] = (_Float16)a.x;  h[1] = (_Float16)a.y;
    h[2] = (_Float16)a.z;  h[3] = (_Float16)a.w;
    h[4] = (_Float16)b4.x; h[5] = (_Float16)b4.y;
    h[6] = (_Float16)b4.z; h[7] = (_Float16)b4.w;
    *(half8*)&Xs[s][p8] = h;
  };

  // accumulate one p-quarter of one mid core into c (x-weighted epilogue)
  auto accum_quarter = [&](int qq, int ci, half8 (&B)[4][2], float (&c)[4][4]) {
    const _Float16* wl = ws + MID_OFF + (size_t)ci * MID_SZ
                       + (size_t)((qq * 64 + w) * 1024) + (size_t)lane * 8;
#pragma unroll 4
    for (int j = 0; j < 8; ++j) {
      const _Float16* fp = wl + (size_t)j * 8192;
      half8 A0 = *(const half8*)fp;
      half8 A1 = *(const half8*)(fp + 512);
      f32x4 d0 = {0.f, 0.f, 0.f, 0.f}, d1 = d0, d2 = d0, d3 = d0;
      d0 = __builtin_amdgcn_mfma_f32_16x16x32_f16(A0, B[0][0], d0, 0, 0, 0);
      d0 = __builtin_amdgcn_mfma_f32_16x16x32_f16(A1, B[0][1], d0, 0, 0, 0);
      d1 = __builtin_amdgcn_mfma_f32_16x16x32_f16(A0, B[1][0], d1, 0, 0, 0);
      d1 = __builtin_amdgcn_mfma_f32_16x16x32_f16(A1, B[1][1], d1, 0, 0, 0);
      d2 = __builtin_amdgcn_mfma_f32_16x16x32_f16(A0, B[2][0], d2, 0, 0, 0);
      d2 = __builtin_amdgcn_mfma_f32_16x16x32_f16(A1, B[2][1], d2, 0, 0, 0);
      d3 = __builtin_amdgcn_mfma_f32_16x16x32_f16(A0, B[3][0], d3, 0, 0, 0);
      d3 = __builtin_amdgcn_mfma_f32_16x16x32_f16(A1, B[3][1], d3, 0, 0, 0);
      int p = qq * 16 + 2 * j + pg;
      float xv0 = (float)Xs[sl][p];
      float xv1 = (float)Xs[16 + sl][p];
      float xv2 = (float)Xs[32 + sl][p];
      float xv3 = (float)Xs[48 + sl][p];
#pragma unroll
      for (int r2 = 0; r2 < 4; ++r2) {
        c[0][r2] += xv0 * d0[r2];
        c[1][r2] += xv1 * d1[r2];
        c[2][r2] += xv2 * d2[r2];
        c[3][r2] += xv3 * d3[r2];
      }
    }
  };

  // ---- v0 = core_last contracted with x[:,7] (all blocks, redundant) ----
  stageX(7);
  __syncthreads();
  {
    int sh = w >> 2, vlt = w & 3;
    half8 A0 = *(const half8*)(ws + LAST_OFF + (size_t)((vlt * 2 + 0) * 64 + lane) * 8);
    half8 A1 = *(const half8*)(ws + LAST_OFF + (size_t)((vlt * 2 + 1) * 64 + lane) * 8);
#pragma unroll
    for (int st2 = 0; st2 < 2; ++st2) {
      int st = sh * 2 + st2;
      half8 b0 = *(const half8*)&Xs[st * 16 + sl][quad * 8];
      half8 b1 = *(const half8*)&Xs[st * 16 + sl][32 + quad * 8];
      f32x4 d = {0.f, 0.f, 0.f, 0.f};
      d = __builtin_amdgcn_mfma_f32_16x16x32_f16(A0, b0, d, 0, 0, 0);
      d = __builtin_amdgcn_mfma_f32_16x16x32_f16(A1, b1, d, 0, 0, 0);
      half4 hv;
#pragma unroll
      for (int r2 = 0; r2 < 4; ++r2) hv[r2] = (_Float16)d[r2];
      *(half4*)&Vc[st * 16 + sl][vlt * 16 + quad * 4] = hv;
    }
  }
  __syncthreads();

  // ---- 6 mid steps, each p-split across the 4-block group ----
  for (int step = 0; step < 6; ++step) {
    const int ci = 5 - step;
    stageX(ci + 1);
    __syncthreads();

    half8 B[4][2];
#pragma unroll
    for (int st = 0; st < 4; ++st) {
      B[st][0] = *(const half8*)&Vc[st * 16 + sl][quad * 8];
      B[st][1] = *(const half8*)&Vc[st * 16 + sl][32 + quad * 8];
    }
    float c[4][4] = {};
    accum_quarter(q, ci, B, c);

#pragma unroll
    for (int st = 0; st < 4; ++st) {
      half4 hv;
#pragma unroll
      for (int r2 = 0; r2 < 4; ++r2) hv[r2] = (_Float16)c[st][r2];
      *(half4*)&Vt[pg][st * 16 + sl][lt * 16 + quad * 4] = hv;
    }
    __syncthreads();

    // combine own 2 pg-partials; publish own quarter (f16, agent atomics)
    half8 t0 = *(const half8*)&Vt[0][cs][l8];
    half8 t1 = *(const half8*)&Vt[1][cs][l8];
    float own[8];
#pragma unroll
    for (int k2 = 0; k2 < 8; ++k2) own[k2] = (float)t0[k2] + (float)t1[k2];
    {
      union { u64 u[2]; half8 h; } pu;
#pragma unroll
      for (int k2 = 0; k2 < 8; ++k2) pu.h[k2] = (_Float16)own[k2];
      u64* dst = (u64*)((char*)ws + PART_BYTE_OFF
                 + ((size_t)((step * 64 + g) * 4 + q) * 8192)
                 + (size_t)(cs * 64 + l8) * 2);
      __hip_atomic_store(dst + 0, pu.u[0], __ATOMIC_RELAXED, __HIP_MEMORY_SCOPE_AGENT);
      __hip_atomic_store(dst + 1, pu.u[1], __ATOMIC_RELAXED, __HIP_MEMORY_SCOPE_AGENT);
    }
    __threadfence();
    __syncthreads();

    if (tid == 0) {
      unsigned base = (unsigned)(step * 64 + g) * 4;
      __hip_atomic_store(&flags[base + q], 1u, __ATOMIC_RELEASE, __HIP_MEMORY_SCOPE_AGENT);
      int got[4] = {0, 0, 0, 0};
      got[q] = 2;
      for (int it = 0;; ++it) {
        int done = 1;
#pragma unroll
        for (int qq = 0; qq < 4; ++qq) {
          if (!got[qq]) {
            got[qq] = (int)__hip_atomic_load(&flags[base + qq], __ATOMIC_ACQUIRE,
                                             __HIP_MEMORY_SCOPE_AGENT);
            if (!got[qq]) done = 0;
          }
        }
        if (done || it >= POLL_MAX) break;
        __builtin_amdgcn_s_sleep(2);
      }
      status[0] = got[0]; status[1] = got[1];
      status[2] = got[2]; status[3] = got[3];
    }
    __syncthreads();

    // fallback: compute any missing partner quarter locally (rare/pathological)
    int nmiss = (status[0] == 0) + (status[1] == 0) + (status[2] == 0) + (status[3] == 0);
    if (__builtin_expect(nmiss > 0, 0)) {
      for (int qq = 0; qq < 4; ++qq)
        if (status[qq] == 0) accum_quarter(qq, ci, B, c);
#pragma unroll
      for (int st = 0; st < 4; ++st) {
        half4 hv;
#pragma unroll
        for (int r2 = 0; r2 < 4; ++r2) hv[r2] = (_Float16)c[st][r2];
        *(half4*)&Vt[pg][st * 16 + sl][lt * 16 + quad * 4] = hv;
      }
      __syncthreads();
      half8 u0 = *(const half8*)&Vt[0][cs][l8];
      half8 u1 = *(const half8*)&Vt[1][cs][l8];
#pragma unroll
      for (int k2 = 0; k2 < 8; ++k2) own[k2] = (float)u0[k2] + (float)u1[k2];
    }

    // assemble v_new = own (+fallback quarters) + received remote quarters
    float acc[8];
#pragma unroll
    for (int k2 = 0; k2 < 8; ++k2) acc[k2] = own[k2];
#pragma unroll
    for (int qq = 0; qq < 4; ++qq) {
      if (qq != q && status[qq] != 0) {
        const u64* srcp = (const u64*)((const char*)ws + PART_BYTE_OFF
                     + ((size_t)((step * 64 + g) * 4 + qq) * 8192)
                     + (size_t)(cs * 64 + l8) * 2);
        union { u64 u[2]; half8 h; } pu;
        pu.u[0] = __hip_atomic_load(srcp + 0, __ATOMIC_RELAXED, __HIP_MEMORY_SCOPE_AGENT);
        pu.u[1] = __hip_atomic_load(srcp + 1, __ATOMIC_RELAXED, __HIP_MEMORY_SCOPE_AGENT);
#pragma unroll
        for (int k2 = 0; k2 < 8; ++k2) acc[k2] += (float)pu.h[k2];
      }
    }
    half8 nh;
#pragma unroll
    for (int k2 = 0; k2 < 8; ++k2) nh[k2] = (_Float16)acc[k2];
    *(half8*)&Vc[cs][l8] = nh;
    __syncthreads();
  }

  // ---- final: core_first, p-split; LDS reduce then atomicAdd to out ----
  stageX(0);
  {
    float* rl = &RedL[0][0];
    for (int i = tid; i < 10 * 68; i += 512) rl[i] = 0.f;
  }
  __syncthreads();
  {
    half8 B[4][2];
#pragma unroll
    for (int st = 0; st < 4; ++st) {
      B[st][0] = *(const half8*)&Vc[st * 16 + sl][quad * 8];
      B[st][1] = *(const half8*)&Vc[st * 16 + sl][32 + quad * 8];
    }
    float c[4][4] = {};
#pragma unroll
    for (int j = 0; j < 2; ++j) {
      int t = q * 16 + j * 8 + w;     // t == p
      const _Float16* fp = ws + FIRST_OFF + (size_t)(t * 2) * 512 + (size_t)lane * 8;
      half8 A0 = *(const half8*)fp;
      half8 A1 = *(const half8*)(fp + 512);
      f32x4 d0 = {0.f, 0.f, 0.f, 0.f}, d1 = d0, d2 = d0, d3 = d0;
      d0 = __builtin_amdgcn_mfma_f32_16x16x32_f16(A0, B[0][0], d0, 0, 0, 0);
      d0 = __builtin_amdgcn_mfma_f32_16x16x32_f16(A1, B[0][1], d0, 0, 0, 0);
      d1 = __builtin_amdgcn_mfma_f32_16x16x32_f16(A0, B[1][0], d1, 0, 0, 0);
      d1 = __builtin_amdgcn_mfma_f32_16x16x32_f16(A1, B[1][1], d1, 0, 0, 0);
      d2 = __builtin_amdgcn_mfma_f32_16x16x32_f16(A0, B[2][0], d2, 0, 0, 0);
      d2 = __builtin_amdgcn_mfma_f32_16x16x32_f16(A1, B[2][1], d2, 0, 0, 0);
      d3 = __builtin_amdgcn_mfma_f32_16x16x32_f16(A0, B[3][0], d3, 0, 0, 0);
      d3 = __builtin_amdgcn_mfma_f32_16x16x32_f16(A1, B[3][1], d3, 0, 0, 0);
      float xv0 = (float)Xs[sl][t];
      float xv1 = (float)Xs[16 + sl][t];
      float xv2 = (float)Xs[32 + sl][t];
      float xv3 = (float)Xs[48 + sl][t];
#pragma unroll
      for (int r2 = 0; r2 < 4; ++r2) {
        c[0][r2] += xv0 * d0[r2];
        c[1][r2] += xv1 * d1[r2];
        c[2][r2] += xv2 * d2[r2];
        c[3][r2] += xv3 * d3[r2];
      }
    }
#pragma unroll
    for (int st = 0; st < 4; ++st)
#pragma unroll
      for (int r2 = 0; r2 < 4; ++r2) {
        int cc = quad * 4 + r2;
        if (cc < 10) atomicAdd(&RedL[cc][st * 16 + sl], c[st][r2]);
      }
  }
  __syncthreads();
  for (int i = tid; i < 640; i += 512) {        // 10 classes x 64 samples
    int cc = i >> 6, s = i & 63;
    atomicAdd(&out[(size_t)(s0 + s) * 10 + cc], RedL[cc][s]);
  }
}

extern "C" void kernel_launch(void* const* d_in, const int* in_sizes, int n_in,
                              void* d_out, int out_size, void* d_ws, size_t ws_size,
                              hipStream_t stream) {
  const float* x  = (const float*)d_in[0];   // (4096,8,64)
  const float* cf = (const float*)d_in[1];   // (10,64,64)
  const float* cm = (const float*)d_in[2];   // (6,64,64,64)
  const float* cl = (const float*)d_in[3];   // (64,64)
  _Float16* ws = (_Float16*)d_ws;
  float* out = (float*)d_out;
  tt_swz<<<dim3((SWZ_TOTAL + 255) / 256), dim3(256), 0, stream>>>(cf, cm, cl, ws, out);
  tt_main<<<dim3(256), dim3(512), 0, stream>>>(x, ws, out);
}

// Round 3
// 107.862 us; speedup vs baseline: 3.1435x; 3.1435x over previous
//
#include <hip/hip_runtime.h>

// Tensor-train forward, B=4096 N=8 F=64 D=64 C=10.
// R4: revert to R1 structure (p-split via inter-block sync abandoned:
// agent-scope release/acquire across non-coherent XCD L2s cost ~40us/step,
// 280us total, all pipes idle). R1 base: 32 samples/block (128 blocks x
// 1024 thr), v-chain right-to-left, per step a f16 MFMA GEMM
// W[(p,l),s]=A'[(p,l),r]*v[s,r] with x[s,p]-weighted p-reduction fused in
// the D-fragment epilogue.
// R4 deltas vs R1: (a) inner loop unroll 4->8 to deepen A-load hoisting
// (VGPR capped at 128 by launch_bounds, 4 waves/SIMD preserved);
// (b) s_setprio(1/0) around MFMA clusters (waves not barrier-locked between
// steps -> scheduler role diversity exists); (c) x scalar LDS reads hoisted
// above the MFMA cluster.

typedef _Float16 half8 __attribute__((ext_vector_type(8)));
typedef _Float16 half4 __attribute__((ext_vector_type(4)));
typedef _Float16 half2v __attribute__((ext_vector_type(2)));
typedef float f32x4 __attribute__((ext_vector_type(4)));

#define LAST_OFF   0          // 4 tiles * 2 kt * 64 lanes * 8 halves
#define MID_OFF    4096
#define MID_SZ     262144     // per mid core: 256 tiles * 2 * 64 * 8
#define FIRST_OFF  1576960    // 4096 + 6*262144
#define N_FRAGS    3208

// ---------- prologue: fp32 cores -> f16, MFMA-A-fragment swizzled ----------
__global__ __launch_bounds__(256) void tt_swz(
    const float* __restrict__ cf,   // core_first (10,64,64)  [c][p][r]
    const float* __restrict__ cm,   // cores_mid  (6,64,64,64)[ci][l][p][r]
    const float* __restrict__ cl,   // core_last  (64,64)     [l][p]
    _Float16* __restrict__ ws)
{
  int gid = blockIdx.x * 256 + threadIdx.x;
  if (gid >= N_FRAGS * 64) return;
  int lane = gid & 63, frag = gid >> 6;
  int quad = lane >> 4, m16 = lane & 15;
  half8 hv;
  _Float16* dst;
  if (frag < 8) {                       // core_last: rows l (4 tiles), k = p
    int t = frag >> 1, kt = frag & 1;
    int l = t * 16 + m16;
    const float* s = cl + l * 64 + kt * 32 + quad * 8;
#pragma unroll
    for (int j = 0; j < 8; ++j) hv[j] = (_Float16)s[j];
    dst = ws + LAST_OFF + (size_t)((t * 2 + kt) * 64 + lane) * 8;
  } else if (frag < 8 + 3072) {         // mid cores: rows (p,l), k = r
    int f2 = frag - 8;
    int ci = f2 >> 9, rem = f2 & 511;
    int t = rem >> 1, kt = rem & 1;
    int l = (t & 3) * 16 + m16, p = t >> 2;
    const float* s = cm + (((size_t)ci * 64 + l) * 64 + p) * 64 + kt * 32 + quad * 8;
#pragma unroll
    for (int j = 0; j < 8; ++j) hv[j] = (_Float16)s[j];
    dst = ws + MID_OFF + (size_t)ci * MID_SZ + (size_t)(rem * 64 + lane) * 8;
  } else {                              // core_first: rows c (pad 16), k = r
    int f2 = frag - 3080;
    int t = f2 >> 1, kt = f2 & 1;
    int c = m16, p = t;
    if (c < 10) {
      const float* s = cf + ((size_t)(c * 64 + p)) * 64 + kt * 32 + quad * 8;
#pragma unroll
      for (int j = 0; j < 8; ++j) hv[j] = (_Float16)s[j];
    } else {
#pragma unroll
      for (int j = 0; j < 8; ++j) hv[j] = (_Float16)0.f;
    }
    dst = ws + FIRST_OFF + (size_t)((t * 2 + kt) * 64 + lane) * 8;
  }
  *(half8*)dst = hv;
}

// ------------------- main chain: 128 blocks x 1024 threads -----------------
__global__ __launch_bounds__(1024) void tt_main(
    const float* __restrict__ x,        // (4096, 8, 64)
    const _Float16* __restrict__ ws,
    float* __restrict__ out)            // (4096, 10)
{
  __shared__ __align__(16) _Float16 Xs[512][33];     // [n*64+p][s] f16
  __shared__ __align__(16) _Float16 Vt[4][32][72];   // partials [part][s][l]
  __shared__ __align__(16) _Float16 Vc[32][72];      // combined  [s][r]
  const int tid = threadIdx.x;
  const int w = tid >> 6, lane = tid & 63;
  const int quad = lane >> 4, sl = lane & 15;
  const int blk = blockIdx.x;

  // ---- stage x (32 samples x 512 floats -> f16), zero spare Vt partials ----
  {
    const float* xb = x + (size_t)blk * 32 * 512;
    int s = tid >> 5, q = tid & 31;
#pragma unroll
    for (int k = 0; k < 4; ++k) {
      int f4 = q + 32 * k;
      float4 v = *(const float4*)(xb + (size_t)s * 512 + (size_t)f4 * 4);
      int row = f4 * 4;
      Xs[row + 0][s] = (_Float16)v.x;
      Xs[row + 1][s] = (_Float16)v.y;
      Xs[row + 2][s] = (_Float16)v.z;
      Xs[row + 3][s] = (_Float16)v.w;
    }
    _Float16* vz = &Vt[2][0][0];
    for (int idx = tid; idx < 2 * 32 * 72; idx += 1024) vz[idx] = (_Float16)0.f;
  }
  __syncthreads();

  // ---- GEMM1 (core_last): 16 wave-tasks = (st, kt, tt) ----
  {
    int st = w >> 3, kt = (w >> 2) & 1, tt = w & 3;
    half8 b;
#pragma unroll
    for (int j = 0; j < 8; ++j)
      b[j] = Xs[448 + kt * 32 + quad * 8 + j][st * 16 + sl];
    half8 a = *(const half8*)(ws + LAST_OFF + (size_t)((tt * 2 + kt) * 64 + lane) * 8);
    f32x4 d = {0.f, 0.f, 0.f, 0.f};
    d = __builtin_amdgcn_mfma_f32_16x16x32_f16(a, b, d, 0, 0, 0);
    half4 hv;
#pragma unroll
    for (int r = 0; r < 4; ++r) hv[r] = (_Float16)d[r];
    *(half4*)&Vt[kt][st * 16 + sl][tt * 16 + quad * 4] = hv;
  }
  __syncthreads();
  // combine partials -> Vc
  {
    int s = tid >> 5, rp = tid & 31;
    float r0 = 0.f, r1 = 0.f;
#pragma unroll
    for (int p = 0; p < 4; ++p) {
      half2v h = *(const half2v*)&Vt[p][s][rp * 2];
      r0 += (float)h[0]; r1 += (float)h[1];
    }
    half2v o; o[0] = (_Float16)r0; o[1] = (_Float16)r1;
    *(half2v*)&Vc[s][rp * 2] = o;
  }
  __syncthreads();

  const int g = w & 3, part = w >> 2;
  // ---- 6 middle steps (cores_mid[5] .. cores_mid[0]) ----
  for (int step = 0; step < 6; ++step) {
    int ci = 5 - step;
    // B-frags for both sample tiles & k-halves (single ds_read_b128 each)
    half8 b00 = *(const half8*)&Vc[sl][quad * 8];
    half8 b01 = *(const half8*)&Vc[sl][32 + quad * 8];
    half8 b10 = *(const half8*)&Vc[16 + sl][quad * 8];
    half8 b11 = *(const half8*)&Vc[16 + sl][32 + quad * 8];
    const _Float16* wl = ws + MID_OFF + (size_t)ci * MID_SZ
                       + (size_t)w * 1024 + (size_t)lane * 8;
    float c00 = 0.f, c01 = 0.f, c02 = 0.f, c03 = 0.f;
    float c10 = 0.f, c11 = 0.f, c12 = 0.f, c13 = 0.f;
    const int xrow = (ci + 1) * 64;
#pragma unroll 8
    for (int j = 0; j < 16; ++j) {
      int t = j * 16 + w;                       // p = t>>2 == 4j + (w>>2)
      int p = t >> 2;
      const _Float16* fp = wl + (size_t)j * 16384;
      half8 A0 = *(const half8*)fp;
      half8 A1 = *(const half8*)(fp + 512);
      float xv0 = (float)Xs[xrow + p][sl];
      float xv1 = (float)Xs[xrow + p][16 + sl];
      f32x4 d0 = {0.f, 0.f, 0.f, 0.f}, d1 = {0.f, 0.f, 0.f, 0.f};
      __builtin_amdgcn_s_setprio(1);
      d0 = __builtin_amdgcn_mfma_f32_16x16x32_f16(A0, b00, d0, 0, 0, 0);
      d0 = __builtin_amdgcn_mfma_f32_16x16x32_f16(A1, b01, d0, 0, 0, 0);
      d1 = __builtin_amdgcn_mfma_f32_16x16x32_f16(A0, b10, d1, 0, 0, 0);
      d1 = __builtin_amdgcn_mfma_f32_16x16x32_f16(A1, b11, d1, 0, 0, 0);
      __builtin_amdgcn_s_setprio(0);
      c00 += xv0 * d0[0]; c01 += xv0 * d0[1]; c02 += xv0 * d0[2]; c03 += xv0 * d0[3];
      c10 += xv1 * d1[0]; c11 += xv1 * d1[1]; c12 += xv1 * d1[2]; c13 += xv1 * d1[3];
    }
    half4 h0, h1;
    h0[0] = (_Float16)c00; h0[1] = (_Float16)c01; h0[2] = (_Float16)c02; h0[3] = (_Float16)c03;
    h1[0] = (_Float16)c10; h1[1] = (_Float16)c11; h1[2] = (_Float16)c12; h1[3] = (_Float16)c13;
    *(half4*)&Vt[part][sl][g * 16 + quad * 4] = h0;
    *(half4*)&Vt[part][16 + sl][g * 16 + quad * 4] = h1;
    __syncthreads();
    {
      int s = tid >> 5, rp = tid & 31;
      float r0 = 0.f, r1 = 0.f;
#pragma unroll
      for (int p = 0; p < 4; ++p) {
        half2v h = *(const half2v*)&Vt[p][s][rp * 2];
        r0 += (float)h[0]; r1 += (float)h[1];
      }
      half2v o; o[0] = (_Float16)r0; o[1] = (_Float16)r1;
      *(half2v*)&Vc[s][rp * 2] = o;
    }
    __syncthreads();
  }

  // ---- final (core_first): 8 waves, 64 tiles (t = p); Red overlays Vt ----
  float* Red = (float*)&Vt[0][0][0];              // [8][10][32]
  if (w < 8) {
    half8 b00 = *(const half8*)&Vc[sl][quad * 8];
    half8 b01 = *(const half8*)&Vc[sl][32 + quad * 8];
    half8 b10 = *(const half8*)&Vc[16 + sl][quad * 8];
    half8 b11 = *(const half8*)&Vc[16 + sl][32 + quad * 8];
    float f00 = 0.f, f01 = 0.f, f02 = 0.f, f03 = 0.f;
    float f10 = 0.f, f11 = 0.f, f12 = 0.f, f13 = 0.f;
#pragma unroll
    for (int j = 0; j < 8; ++j) {
      int t = j * 8 + w;
      const _Float16* fp = ws + FIRST_OFF + (size_t)t * 1024 + (size_t)lane * 8;
      half8 A0 = *(const half8*)fp;
      half8 A1 = *(const half8*)(fp + 512);
      float xv0 = (float)Xs[t][sl];
      float xv1 = (float)Xs[t][16 + sl];
      f32x4 d0 = {0.f, 0.f, 0.f, 0.f}, d1 = {0.f, 0.f, 0.f, 0.f};
      __builtin_amdgcn_s_setprio(1);
      d0 = __builtin_amdgcn_mfma_f32_16x16x32_f16(A0, b00, d0, 0, 0, 0);
      d0 = __builtin_amdgcn_mfma_f32_16x16x32_f16(A1, b01, d0, 0, 0, 0);
      d1 = __builtin_amdgcn_mfma_f32_16x16x32_f16(A0, b10, d1, 0, 0, 0);
      d1 = __builtin_amdgcn_mfma_f32_16x16x32_f16(A1, b11, d1, 0, 0, 0);
      __builtin_amdgcn_s_setprio(0);
      f00 += xv0 * d0[0]; f01 += xv0 * d0[1]; f02 += xv0 * d0[2]; f03 += xv0 * d0[3];
      f10 += xv1 * d1[0]; f11 += xv1 * d1[1]; f12 += xv1 * d1[2]; f13 += xv1 * d1[3];
    }
    float a0[4] = {f00, f01, f02, f03};
    float a1[4] = {f10, f11, f12, f13};
#pragma unroll
    for (int r = 0; r < 4; ++r) {
      int c = quad * 4 + r;
      if (c < 10) {
        Red[(w * 10 + c) * 32 + sl] = a0[r];
        Red[(w * 10 + c) * 32 + 16 + sl] = a1[r];
      }
    }
  }
  __syncthreads();
  if (tid < 320) {
    int c = tid >> 5, s = tid & 31;
    float sum = 0.f;
#pragma unroll
    for (int ww = 0; ww < 8; ++ww) sum += Red[(ww * 10 + c) * 32 + s];
    out[((size_t)blk * 32 + s) * 10 + c] = sum;
  }
}

extern "C" void kernel_launch(void* const* d_in, const int* in_sizes, int n_in,
                              void* d_out, int out_size, void* d_ws, size_t ws_size,
                              hipStream_t stream) {
  const float* x  = (const float*)d_in[0];   // (4096,8,64)
  const float* cf = (const float*)d_in[1];   // (10,64,64)
  const float* cm = (const float*)d_in[2];   // (6,64,64,64)
  const float* cl = (const float*)d_in[3];   // (64,64)
  _Float16* ws = (_Float16*)d_ws;            // ~3.3 MB used
  float* out = (float*)d_out;
  tt_swz<<<dim3((N_FRAGS * 64 + 255) / 256), dim3(256), 0, stream>>>(cf, cm, cl, ws);
  tt_main<<<dim3(128), dim3(1024), 0, stream>>>(x, ws, out);
}